// Round 2
// baseline (450.695 us; speedup 1.0000x reference)
//
#include <hip/hip_runtime.h>

typedef __bf16 bf16;
typedef __bf16 bf16x2 __attribute__((ext_vector_type(2)));
typedef __bf16 bf16x8 __attribute__((ext_vector_type(8)));
typedef float  f32x4  __attribute__((ext_vector_type(4)));

#define MFMA16(a,b,c) __builtin_amdgcn_mfma_f32_16x16x32_bf16(a,b,c,0,0,0)

constexpr int SEQ   = 2048;
constexpr int NH    = 16;
constexpr int HD    = 64;
constexpr int BATCH = 4;
constexpr int DM    = 1024;          // model dim
constexpr int ROWS  = BATCH * SEQ;   // 8192
constexpr size_t TEN = (size_t)BATCH * NH * SEQ * HD;   // 8,388,608 elems per tensor

// ---------------------------------------------------------------- convert x
__global__ __launch_bounds__(256) void k_convert_x(const float* __restrict__ x,
                                                   bf16* __restrict__ xb) {
    size_t idx = ((size_t)blockIdx.x * 256 + threadIdx.x) * 8;
    float4 f0 = *(const float4*)(x + idx);
    float4 f1 = *(const float4*)(x + idx + 4);
    bf16x8 o;
    o[0] = (bf16)f0.x; o[1] = (bf16)f0.y; o[2] = (bf16)f0.z; o[3] = (bf16)f0.w;
    o[4] = (bf16)f1.x; o[5] = (bf16)f1.y; o[6] = (bf16)f1.z; o[7] = (bf16)f1.w;
    *(bf16x8*)(xb + idx) = o;
}

// ------------------------------------------- weight transpose+convert (fp32 W[k][n] -> bf16 Wt[n][k])
__global__ __launch_bounds__(256) void k_wtrans(const float* __restrict__ W0,
                                                const float* __restrict__ W1,
                                                const float* __restrict__ W2,
                                                const float* __restrict__ W3,
                                                bf16* __restrict__ Wt_all) {
    __shared__ float T[64][65];
    const int z = blockIdx.z;
    const float* W = (z == 0) ? W0 : (z == 1) ? W1 : (z == 2) ? W2 : W3;
    bf16* Wt = Wt_all + (size_t)z * DM * DM;
    const int t = threadIdx.x;
    const int kb = blockIdx.x, nb = blockIdx.y;
    const int rl = t >> 2, seg = t & 3;
    const float* src = W + (size_t)(kb * 64 + rl) * DM + nb * 64 + seg * 16;
#pragma unroll
    for (int j4 = 0; j4 < 4; j4++) {
        float4 f = *(const float4*)(src + j4 * 4);
        T[rl][seg * 16 + j4 * 4 + 0] = f.x;
        T[rl][seg * 16 + j4 * 4 + 1] = f.y;
        T[rl][seg * 16 + j4 * 4 + 2] = f.z;
        T[rl][seg * 16 + j4 * 4 + 3] = f.w;
    }
    __syncthreads();
    bf16* dst = Wt + (size_t)(nb * 64 + rl) * DM + kb * 64 + seg * 16;
    bf16x8 o0, o1;
#pragma unroll
    for (int j = 0; j < 8; j++) {
        o0[j] = (bf16)T[seg * 16 + j][rl];
        o1[j] = (bf16)T[seg * 16 + 8 + j][rl];
    }
    *(bf16x8*)dst = o0;
    *(bf16x8*)(dst + 8) = o1;
}

// ---------------------------------------------------------------- GEMM
// C[M,N] = A[M,K] @ W[K,N] + bias, A bf16 row-major, W given transposed (Wt[n][k]).
// MODE 0: out = bf16, scattered to [B,H,S,D] (+ z*TEN).  MODE 1: out = fp32 [row][col].
template <int MODE>
__global__ __launch_bounds__(256) void k_gemm(const bf16* __restrict__ A,
                                              const bf16* __restrict__ Wt0,
                                              const float* __restrict__ b0,
                                              const float* __restrict__ b1,
                                              const float* __restrict__ b2,
                                              void* __restrict__ out) {
    __shared__ __align__(16) bf16 As[128][40];   // pad 32->40: 2-way conflicts only
    __shared__ __align__(16) bf16 Bs[128][40];
    const int z = blockIdx.z;
    const bf16* Wt = Wt0 + (size_t)z * DM * DM;
    const float* bias = (z == 0) ? b0 : (z == 1) ? b1 : b2;

    const int t = threadIdx.x;
    const int w = t >> 6, lane = t & 63, quad = lane >> 4, l16 = lane & 15;
    const int bm = blockIdx.y * 128, bn = blockIdx.x * 128;
    const int wm = (w >> 1) * 64, wn = (w & 1) * 64;
    const int r = t >> 1, half = t & 1;

    const bf16* aptr = A + (size_t)(bm + r) * DM + half * 16;
    const bf16* bptr = Wt + (size_t)(bn + r) * DM + half * 16;

    f32x4 zero = {0.f, 0.f, 0.f, 0.f};
    f32x4 acc[4][4];
#pragma unroll
    for (int mt = 0; mt < 4; mt++) {
#pragma unroll
        for (int nt = 0; nt < 4; nt++) acc[mt][nt] = zero;
    }

    for (int k0 = 0; k0 < DM; k0 += 32) {
        bf16x8 a0 = *(const bf16x8*)aptr;
        bf16x8 a1 = *(const bf16x8*)(aptr + 8);
        bf16x8 bb0 = *(const bf16x8*)bptr;
        bf16x8 bb1 = *(const bf16x8*)(bptr + 8);
        aptr += 32; bptr += 32;
        __syncthreads();   // prior iteration finished reading LDS
        *(bf16x8*)&As[r][half * 16]     = a0;
        *(bf16x8*)&As[r][half * 16 + 8] = a1;
        *(bf16x8*)&Bs[r][half * 16]     = bb0;
        *(bf16x8*)&Bs[r][half * 16 + 8] = bb1;
        __syncthreads();
        bf16x8 af[4], bfr[4];
#pragma unroll
        for (int mt = 0; mt < 4; mt++)
            af[mt] = *(const bf16x8*)&As[wm + mt * 16 + l16][quad * 8];
#pragma unroll
        for (int nt = 0; nt < 4; nt++)
            bfr[nt] = *(const bf16x8*)&Bs[wn + nt * 16 + l16][quad * 8];
#pragma unroll
        for (int mt = 0; mt < 4; mt++) {
#pragma unroll
            for (int nt = 0; nt < 4; nt++)
                acc[mt][nt] = MFMA16(af[mt], bfr[nt], acc[mt][nt]);
        }
    }

    float bv[4];
#pragma unroll
    for (int nt = 0; nt < 4; nt++) bv[nt] = bias[bn + wn + nt * 16 + l16];

#pragma unroll
    for (int mt = 0; mt < 4; mt++) {
#pragma unroll
        for (int nt = 0; nt < 4; nt++) {
            const int col = bn + wn + nt * 16 + l16;
#pragma unroll
            for (int rg = 0; rg < 4; rg++) {
                const int row = bm + wm + mt * 16 + quad * 4 + rg;
                const float val = acc[mt][nt][rg] + bv[nt];
                if (MODE == 0) {
                    const int b = row >> 11, s = row & (SEQ - 1);
                    const int h = col >> 6, dd = col & 63;
                    ((bf16*)out)[(size_t)z * TEN +
                                 (((size_t)(b * NH + h)) * SEQ + s) * HD + dd] = (bf16)val;
                } else {
                    ((float*)out)[(size_t)row * DM + col] = val;
                }
            }
        }
    }
}

// ---------------------------------------------------------------- RoPE (in-place on q,k; q pre-scaled by 1/8)
__global__ __launch_bounds__(256) void k_rope(bf16* __restrict__ q, bf16* __restrict__ k) {
    const int tid = blockIdx.x * 256 + threadIdx.x;   // one (bh, s, pair) per thread
    const int i  = tid & 31;                          // pair index 0..31
    const int s  = (tid >> 5) & (SEQ - 1);
    const int bh = tid >> 16;
    const size_t base = ((size_t)bh * SEQ + s) * HD + 2 * i;
    const float inv_freq = expf(-(float)i * 0.28782313662425574f);  // ln(10000)/32
    const float ang = (float)s * inv_freq;
    float sn, cs;
    sincosf(ang, &sn, &cs);
    bf16x2 qv = *(bf16x2*)(q + base);
    bf16x2 kv = *(bf16x2*)(k + base);
    const float q0 = (float)qv[0], q1 = (float)qv[1];
    const float k0 = (float)kv[0], k1 = (float)kv[1];
    bf16x2 qo, ko;
    qo[0] = (bf16)((q0 * cs - q1 * sn) * 0.125f);
    qo[1] = (bf16)((q1 * cs + q0 * sn) * 0.125f);
    ko[0] = (bf16)(k0 * cs - k1 * sn);
    ko[1] = (bf16)(k1 * cs + k0 * sn);
    *(bf16x2*)(q + base) = qo;
    *(bf16x2*)(k + base) = ko;
}

// ---------------------------------------------------------------- V transpose: [B,H,S,D] -> [B,H,D,S]
__global__ __launch_bounds__(256) void k_vtrans(const bf16* __restrict__ v, bf16* __restrict__ vt) {
    __shared__ float T[64][65];
    const int t = threadIdx.x;
    const int sb = blockIdx.x, bh = blockIdx.y;
    const int rl = t >> 2, seg = t & 3;
    const bf16* src = v + ((size_t)bh * SEQ + sb * 64 + rl) * HD + seg * 16;
    bf16x8 i0 = *(const bf16x8*)src;
    bf16x8 i1 = *(const bf16x8*)(src + 8);
#pragma unroll
    for (int j = 0; j < 8; j++) {
        T[rl][seg * 16 + j]     = (float)i0[j];
        T[rl][seg * 16 + 8 + j] = (float)i1[j];
    }
    __syncthreads();
    bf16* dst = vt + ((size_t)bh * HD + rl) * SEQ + sb * 64 + seg * 16;
    bf16x8 o0, o1;
#pragma unroll
    for (int j = 0; j < 8; j++) {
        o0[j] = (bf16)T[seg * 16 + j][rl];
        o1[j] = (bf16)T[seg * 16 + 8 + j][rl];
    }
    *(bf16x8*)dst = o0;
    *(bf16x8*)(dst + 8) = o1;
}

// ---------------------------------------------------------------- flash attention (causal)
// grid: (32 qtiles, 64 bh). 4 waves; wave w owns 16 q rows. Q scale pre-applied.
__global__ __launch_bounds__(256) void k_attn(const bf16* __restrict__ q,
                                              const bf16* __restrict__ k,
                                              const bf16* __restrict__ vt,
                                              bf16* __restrict__ y) {
    __shared__ __align__(16) bf16 Ks[64][72];       // [kv][d], pad 64->72
    __shared__ __align__(16) bf16 Vs[64][72];       // [d][kv] (V^T tile)
    __shared__ __align__(16) bf16 Ps[4][16][72];    // per-wave P scratch
    const int t = threadIdx.x;
    const int w = t >> 6, lane = t & 63, quad = lane >> 4, l16 = lane & 15;
    const int qt = 31 - (int)blockIdx.x;            // heavy tiles dispatch first
    const int bh = blockIdx.y;
    const int b = bh >> 4, h = bh & 15;
    const int rl = t >> 2, seg = t & 3;

    // Q fragments: A-layout, m = l16, k = quad*8 + j (+32 for second half of D)
    const bf16* qrow = q + ((size_t)bh * SEQ + qt * 64 + w * 16 + l16) * HD;
    const bf16x8 qf0 = *(const bf16x8*)(qrow + quad * 8);
    const bf16x8 qf1 = *(const bf16x8*)(qrow + 32 + quad * 8);

    const float NEG_INF = -__builtin_inff();
    float m_i[4], l_i[4];
    f32x4 zero = {0.f, 0.f, 0.f, 0.f};
    f32x4 acc_o[4];
#pragma unroll
    for (int rg = 0; rg < 4; rg++) { m_i[rg] = NEG_INF; l_i[rg] = 0.f; }
#pragma unroll
    for (int nt = 0; nt < 4; nt++) acc_o[nt] = zero;

    const bf16* kbase = k  + (size_t)bh * SEQ * HD;
    const bf16* vbase = vt + (size_t)bh * HD * SEQ;

    for (int kt = 0; kt <= qt; kt++) {
        // ---- stage K tile [64 kv][64 d] and V^T tile [64 d][64 kv]
        const bf16* ks = kbase + (size_t)(kt * 64 + rl) * HD + seg * 16;
        bf16x8 ka  = *(const bf16x8*)ks;
        bf16x8 kb2 = *(const bf16x8*)(ks + 8);
        const bf16* vs = vbase + (size_t)rl * SEQ + kt * 64 + seg * 16;
        bf16x8 va  = *(const bf16x8*)vs;
        bf16x8 vb2 = *(const bf16x8*)(vs + 8);
        __syncthreads();
        *(bf16x8*)&Ks[rl][seg * 16]     = ka;
        *(bf16x8*)&Ks[rl][seg * 16 + 8] = kb2;
        *(bf16x8*)&Vs[rl][seg * 16]     = va;
        *(bf16x8*)&Vs[rl][seg * 16 + 8] = vb2;
        __syncthreads();

        // ---- S = Q K^T  (scores, scale pre-applied to Q)
        f32x4 accs[4];
#pragma unroll
        for (int nt = 0; nt < 4; nt++) {
            bf16x8 kf0 = *(const bf16x8*)&Ks[nt * 16 + l16][quad * 8];
            bf16x8 kf1 = *(const bf16x8*)&Ks[nt * 16 + l16][32 + quad * 8];
            f32x4 a = zero;
            a = MFMA16(qf0, kf0, a);
            a = MFMA16(qf1, kf1, a);
            accs[nt] = a;
        }
        // ---- causal mask (diagonal tile only)
        if (kt == qt) {
#pragma unroll
            for (int nt = 0; nt < 4; nt++) {
                const int kv = kt * 64 + nt * 16 + l16;
#pragma unroll
                for (int rg = 0; rg < 4; rg++) {
                    const int qr = qt * 64 + w * 16 + quad * 4 + rg;
                    if (kv > qr) accs[nt][rg] = NEG_INF;
                }
            }
        }
        // ---- online softmax (per q row = (quad, rg); 16 lanes of quad hold its cols)
        float ps[4][4];
#pragma unroll
        for (int rg = 0; rg < 4; rg++) {
            float rmax = fmaxf(fmaxf(accs[0][rg], accs[1][rg]),
                               fmaxf(accs[2][rg], accs[3][rg]));
            rmax = fmaxf(rmax, __shfl_xor(rmax, 1));
            rmax = fmaxf(rmax, __shfl_xor(rmax, 2));
            rmax = fmaxf(rmax, __shfl_xor(rmax, 4));
            rmax = fmaxf(rmax, __shfl_xor(rmax, 8));
            const float mnew = fmaxf(m_i[rg], rmax);
            const float al = __expf(m_i[rg] - mnew);   // first tile: exp(-inf)=0
            m_i[rg] = mnew;
            float rs = 0.f;
#pragma unroll
            for (int nt = 0; nt < 4; nt++) {
                const float p = __expf(accs[nt][rg] - mnew);
                ps[nt][rg] = p;
                rs += p;
            }
            rs += __shfl_xor(rs, 1);
            rs += __shfl_xor(rs, 2);
            rs += __shfl_xor(rs, 4);
            rs += __shfl_xor(rs, 8);
            l_i[rg] = l_i[rg] * al + rs;
#pragma unroll
            for (int nt = 0; nt < 4; nt++) acc_o[nt][rg] *= al;
        }
        // ---- P: C-layout -> A-layout via LDS round-trip
#pragma unroll
        for (int nt = 0; nt < 4; nt++) {
#pragma unroll
            for (int rg = 0; rg < 4; rg++)
                Ps[w][quad * 4 + rg][nt * 16 + l16] = (bf16)ps[nt][rg];
        }
        __syncthreads();   // conservative: order P write->read
        const bf16x8 pf0 = *(const bf16x8*)&Ps[w][l16][quad * 8];
        const bf16x8 pf1 = *(const bf16x8*)&Ps[w][l16][32 + quad * 8];
        // ---- O += P V
#pragma unroll
        for (int nt = 0; nt < 4; nt++) {
            bf16x8 vf0 = *(const bf16x8*)&Vs[nt * 16 + l16][quad * 8];
            bf16x8 vf1 = *(const bf16x8*)&Vs[nt * 16 + l16][32 + quad * 8];
            acc_o[nt] = MFMA16(pf0, vf0, acc_o[nt]);
            acc_o[nt] = MFMA16(pf1, vf1, acc_o[nt]);
        }
    }

    // ---- epilogue: O / l, store y as [B, S, H*D] bf16
#pragma unroll
    for (int rg = 0; rg < 4; rg++) {
        const float inv = 1.0f / l_i[rg];
        const int s = qt * 64 + w * 16 + quad * 4 + rg;
#pragma unroll
        for (int nt = 0; nt < 4; nt++) {
            const float val = acc_o[nt][rg] * inv;
            y[((size_t)(b * SEQ + s)) * DM + h * HD + nt * 16 + l16] = (bf16)val;
        }
    }
}

// ---------------------------------------------------------------- launch
extern "C" void kernel_launch(void* const* d_in, const int* in_sizes, int n_in,
                              void* d_out, int out_size, void* d_ws, size_t ws_size,
                              hipStream_t stream) {
    const float* x  = (const float*)d_in[0];
    const float* Wq = (const float*)d_in[1];
    const float* bq = (const float*)d_in[2];
    const float* Wk = (const float*)d_in[3];
    const float* bk = (const float*)d_in[4];
    const float* Wv = (const float*)d_in[5];
    const float* bv = (const float*)d_in[6];
    const float* Wo = (const float*)d_in[7];
    const float* bo = (const float*)d_in[8];

    // Workspace layout (88 MB total). Each of q/k/v/vt is TEN = 8,388,608
    // bf16 elements = 16 MB (Round-1 bug: these were halved, overlapping).
    char* ws = (char*)d_ws;
    bf16* xb   = (bf16*)(ws);                       // 16 MB: x bf16; reused as attn out y
    bf16* wall = (bf16*)(ws + (16ull << 20));       //  8 MB: Wq^T,Wk^T,Wv^T,Wo^T bf16
    bf16* qb   = (bf16*)(ws + (24ull << 20));       // 16 MB
    bf16* kb   = (bf16*)(ws + (40ull << 20));       // 16 MB
    bf16* vb   = (bf16*)(ws + (56ull << 20));       // 16 MB
    bf16* vtb  = (bf16*)(ws + (72ull << 20));       // 16 MB: V^T [B,H,D,S]
    bf16* wot  = wall + 3ull * DM * DM;

    k_convert_x<<<4096, 256, 0, stream>>>(x, xb);
    k_wtrans<<<dim3(16, 16, 4), 256, 0, stream>>>(Wq, Wk, Wv, Wo, wall);
    k_gemm<0><<<dim3(8, 64, 3), 256, 0, stream>>>(xb, wall, bq, bk, bv, qb);
    k_rope<<<16384, 256, 0, stream>>>(qb, kb);
    k_vtrans<<<dim3(32, 64), 256, 0, stream>>>(vb, vtb);
    k_attn<<<dim3(32, 64), 256, 0, stream>>>(qb, kb, vtb, xb);
    k_gemm<1><<<dim3(8, 64, 1), 256, 0, stream>>>(xb, wot, bo, bo, bo, d_out);
}